// Round 7
// baseline (556.378 us; speedup 1.0000x reference)
//
#include <hip/hip_runtime.h>
#include <hip/hip_bf16.h>

#define T_STEPS 2048
#define BATCH 16
#define DIM 1024
#define NDIM 64
#define M_TOTAL (T_STEPS * BATCH)  // 32768
#define STRIDE (BATCH * NDIM)      // floats per timestep in Kp/Qp = 1024
#define CH 64                      // recurrence chunk (timesteps per LDS buffer)
#define NLOG2E -1.44269504088896340736f

typedef __attribute__((ext_vector_type(8))) short bf16x8;
typedef __attribute__((ext_vector_type(4))) float f32x4;
typedef __attribute__((ext_vector_type(2))) float f32x2;

__device__ inline unsigned pk_bf(float lo, float hi) {
    __hip_bfloat162 h = __float22bfloat162_rn(float2{lo, hi});
    return *(unsigned*)&h;  // v_cvt_pk_bf16_f32
}

template <int CTRL>
__device__ inline float dpp_add(float x) {
    int v = __builtin_amdgcn_update_dpp(0, __float_as_int(x), CTRL, 0xF, 0xF, true);
    return x + __int_as_float(v);
}
// full sum across contiguous 16-lane rows (result in all 16 lanes)
__device__ inline float red16(float x) {
    x = dpp_add<0xB1>(x);
    x = dpp_add<0x4E>(x);
    x = dpp_add<0x141>(x);
    x = dpp_add<0x140>(x);
    return x;
}

#define AS1 __attribute__((address_space(1)))
#define AS3 __attribute__((address_space(3)))
__device__ inline void gl_lds16(const float* g, float* l) {
    __builtin_amdgcn_global_load_lds((const AS1 unsigned*)g, (AS3 unsigned*)l, 16, 0, 0);
}
__device__ inline void gl_lds4(const float* g, float* l) {
    __builtin_amdgcn_global_load_lds((const AS1 unsigned*)g, (AS3 unsigned*)l, 4, 0, 0);
}
#define WAIT_VM0 do { __builtin_amdgcn_s_waitcnt(0x0F70); asm volatile("" ::: "memory"); } while (0)

// ---------------- W prepack: fp32 -> bf16, row order [K, Q, V, A] ----------------
__global__ __launch_bounds__(256) void pack_w(
    const float* __restrict__ Wk, const float* __restrict__ Wq,
    const float* __restrict__ Wv, const float* __restrict__ Wa,
    unsigned short* __restrict__ Wb) {
    int n = blockIdx.x;  // 0..255
    int sel = n >> 6;
    const float* W = (sel == 0) ? Wk : (sel == 1) ? Wq : (sel == 2) ? Wv : Wa;
    int k4 = threadIdx.x * 4;
    float4 f = *(const float4*)(W + (size_t)(n & 63) * DIM + k4);
    uint2 u;
    u.x = pk_bf(f.x, f.y);
    u.y = pk_bf(f.z, f.w);
    *(uint2*)(Wb + (size_t)n * DIM + k4) = u;
}

// ---------------- projection ----------------
// 512 blocks (2/CU) x 256 thr. Block: 64 m-rows x 256 n. Wave wn = n-quarter
// (0=K 1=Q 2=V 3=A). BK=32. Padded LDS rows: LDA=40 shorts (32 data + 8 pad;
// bank = 20*row mod 32 -> 2-way aliasing = free [m136]). Double-buffered; x read once;
// B prepacked bf16 (no cvt on the B path).
#define LDA 40
__global__ __launch_bounds__(256, 2) void proj_kernel(
    const float* __restrict__ x, const unsigned short* __restrict__ Wb,
    const float* __restrict__ ba, float* __restrict__ Kp, float* __restrict__ Qp,
    float* __restrict__ VAi) {
    __shared__ unsigned short sA[2][64 * LDA];    // 10.2 KB
    __shared__ unsigned short sB[2][256 * LDA];   // 41 KB

    const int m0 = blockIdx.x * 64;
    const int tid = threadIdx.x;
    const int wn = tid >> 6, lane = tid & 63, lrow = lane & 15, quad = lane >> 4;

    f32x4 acc[4][4];  // [mt][nt]
#pragma unroll
    for (int a = 0; a < 4; a++)
#pragma unroll
        for (int b = 0; b < 4; b++) acc[a][b] = (f32x4)(0.f);

    // A loads: row ar = tid>>2 (0..63), 8 floats at col (tid&3)*8
    const int ar = tid >> 2;
    const int acb = (tid & 3) * 8;  // float (and short) offset within BK=32 row
    const float* xg = x + (size_t)(m0 + ar) * DIM + acb;
    // B loads: thread -> full 32-short slice of row tid
    const unsigned short* wg = Wb + (size_t)tid * DIM;

    float4 a4[2];
    uint4 b4[4];
    auto load_globals = [&](int it) {
        const int k0 = it * 32;
        a4[0] = *(const float4*)(xg + k0);
        a4[1] = *(const float4*)(xg + k0 + 4);
#pragma unroll
        for (int j = 0; j < 4; ++j) b4[j] = *(const uint4*)(wg + k0 + j * 8);
    };
    auto cvt_store = [&](int buf) {
        unsigned ap[4];
        ap[0] = pk_bf(a4[0].x, a4[0].y);
        ap[1] = pk_bf(a4[0].z, a4[0].w);
        ap[2] = pk_bf(a4[1].x, a4[1].y);
        ap[3] = pk_bf(a4[1].z, a4[1].w);
        *(uint4*)&sA[buf][ar * LDA + acb] = *(uint4*)&ap[0];
#pragma unroll
        for (int j = 0; j < 4; ++j)
            *(uint4*)&sB[buf][tid * LDA + j * 8] = b4[j];
    };

    load_globals(0);
    cvt_store(0);
    __syncthreads();

    for (int it = 0; it < 32; ++it) {
        const int cur = it & 1;
        if (it < 31) load_globals(it + 1);  // latency hidden under MFMA below

        bf16x8 af[4];
#pragma unroll
        for (int mt = 0; mt < 4; ++mt)
            af[mt] = *(const bf16x8*)&sA[cur][(mt * 16 + lrow) * LDA + quad * 8];
#pragma unroll
        for (int nt = 0; nt < 4; ++nt) {
            bf16x8 bfr = *(const bf16x8*)&sB[cur][(wn * 64 + nt * 16 + lrow) * LDA + quad * 8];
#pragma unroll
            for (int mt = 0; mt < 4; ++mt)
                acc[mt][nt] = __builtin_amdgcn_mfma_f32_16x16x32_bf16(af[mt], bfr, acc[mt][nt], 0, 0, 0);
        }

        if (it < 31) cvt_store(cur ^ 1);
        __syncthreads();
    }

    // epilogue: C/D layout col = lane&15, row = quad*4 + reg  [m89-verified]
    float bav[4];
    if (wn == 3) {
#pragma unroll
        for (int nt = 0; nt < 4; ++nt) bav[nt] = ba[nt * 16 + lrow];
    }
#pragma unroll
    for (int mt = 0; mt < 4; ++mt)
#pragma unroll
        for (int nt = 0; nt < 4; ++nt) {
            int col = nt * 16 + lrow;
#pragma unroll
            for (int reg = 0; reg < 4; ++reg) {
                int m = m0 + mt * 16 + quad * 4 + reg;
                float vvv = acc[mt][nt][reg];
                if (wn == 0) Kp[(size_t)m * 64 + col] = vvv;
                else if (wn == 1) Qp[(size_t)m * 64 + col] = vvv;
                else if (wn == 2) VAi[(size_t)m * 128 + col * 2] = vvv;
                else VAi[(size_t)m * 128 + col * 2 + 1] = NLOG2E * (vvv + bav[nt]);
            }
        }
}

// ---------------- kq[m] = K[m,:] . Q[m,:] ----------------
__global__ __launch_bounds__(256) void kq_kernel(
    const float* __restrict__ Kp, const float* __restrict__ Qp, float* __restrict__ kq) {
    int m = blockIdx.x * 16 + (threadIdx.x >> 4);
    int c = threadIdx.x & 15;
    float4 k = *(const float4*)(Kp + (size_t)m * 64 + c * 4);
    float4 q = *(const float4*)(Qp + (size_t)m * 64 + c * 4);
    float p = k.x * q.x + k.y * q.y + k.z * q.z + k.w * q.w;
    p = red16(p);
    if (c == 0) kq[m] = p;
}

// ---------------- recurrence ----------------
// grid (16 row-groups, 16 batches) x 64; lane = r*16+c; row i = g*4+r, cols c*4..+3
__global__ __launch_bounds__(64, 1) void recur_kernel(
    const float* __restrict__ Kp, const float* __restrict__ Qp,
    const float* __restrict__ VAi, const float* __restrict__ KQp,
    const float* __restrict__ S0, const float* __restrict__ d_alpha,
    float* __restrict__ out, float* __restrict__ Sout) {
    __shared__ float Kl[2][CH][64];   // 32 KB
    __shared__ float Ql[2][CH][64];   // 32 KB
    __shared__ float VAl[2][CH][8];   // 4 KB: [t] = v0,a0,..,v3,a3 (a pre-scaled by -log2e, +ba)
    __shared__ float KQl[2][CH];      // 0.5 KB
    __shared__ float Ol[CH][4];       // 1 KB output staging

    int b = blockIdx.y, g = blockIdx.x, lane = threadIdx.x;
    int r = lane >> 4, c = lane & 15, i = g * 4 + r, c4 = c * 4;

    float4 sv = *(const float4*)(S0 + ((size_t)b * NDIM + i) * NDIM + c4);
    f32x2 s01 = {sv.x, sv.y}, s23 = {sv.z, sv.w};
    float dabar = d_alpha[i] * NLOG2E;

    const float* Kbase = Kp + (size_t)b * NDIM + (size_t)(lane >> 4) * STRIDE + (lane & 15) * 4;
    const float* Qbase = Qp + (size_t)b * NDIM + (size_t)(lane >> 4) * STRIDE + (lane & 15) * 4;
    const float* VAbase = VAi + (size_t)b * 128 + g * 8 + (lane & 1) * 4 + (size_t)(lane >> 1) * 2048;
    const float* KQbase = KQp + b + (size_t)lane * BATCH;

    auto load_chunk = [&](int t0, int buf) {
#pragma unroll
        for (int j = 0; j < 16; ++j) {
            gl_lds16(Kbase + (size_t)(t0 + j * 4) * STRIDE, &Kl[buf][j * 4][0]);
            gl_lds16(Qbase + (size_t)(t0 + j * 4) * STRIDE, &Ql[buf][j * 4][0]);
        }
        gl_lds16(VAbase + (size_t)t0 * 2048, &VAl[buf][0][0]);
        gl_lds16(VAbase + (size_t)(t0 + 32) * 2048, &VAl[buf][32][0]);
        gl_lds4(KQbase + (size_t)t0 * BATCH, &KQl[buf][0]);
    };

    load_chunk(0, 0);
    WAIT_VM0;

    // depth-2 LDS->reg pipeline
    f32x2 k01[2], k23[2], q01[2], q23[2], va[2];
    float kqv[2];
#pragma unroll
    for (int u = 0; u < 2; ++u) {
        f32x4 kk = *(const f32x4*)(&Kl[0][u][c4]);
        f32x4 qq = *(const f32x4*)(&Ql[0][u][c4]);
        k01[u] = kk.lo; k23[u] = kk.hi;
        q01[u] = qq.lo; q23[u] = qq.hi;
        va[u] = *(const f32x2*)&VAl[0][u][r * 2];
        kqv[u] = KQl[0][u];
    }

    for (int j = 0; j < T_STEPS / CH; ++j) {
        int cb = j & 1;
        if (j + 1 < T_STEPS / CH) load_chunk((j + 1) * CH, cb ^ 1);

        const float* Kb = &Kl[cb][0][0];
        const float* Qb = &Ql[cb][0][0];
        const float* Vb = &VAl[cb][0][0];
        const float* Qk = &KQl[cb][0];

#pragma unroll
        for (int tl = 0; tl < CH; ++tl) {
            int sl = tl & 1;
            f32x2 k0v = k01[sl], k1v = k23[sl], q0v = q01[sl], q1v = q23[sl];
            f32x2 vva = va[sl];
            float kq = kqv[sl];
            if (tl < CH - 2) {
                f32x4 kk = *(const f32x4*)(Kb + (tl + 2) * 64 + c4);
                f32x4 qq = *(const f32x4*)(Qb + (tl + 2) * 64 + c4);
                k01[sl] = kk.lo; k23[sl] = kk.hi;
                q01[sl] = qq.lo; q23[sl] = qq.hi;
                va[sl] = *(const f32x2*)&Vb[(tl + 2) * 8 + r * 2];
                kqv[sl] = Qk[tl + 2];
            }

            f32x2 pk_ = k0v * s01;
            f32x2 pq_ = q0v * s01;
            pk_ = k1v * s23 + pk_;
            pq_ = q1v * s23 + pq_;
            // interleaved DPP ladders (fills VALU->DPP hazard slots)
            float rk = pk_.x + pk_.y;
            float rq = pq_.x + pq_.y;
            rk = dpp_add<0xB1>(rk);  rq = dpp_add<0xB1>(rq);
            rk = dpp_add<0x4E>(rk);  rq = dpp_add<0x4E>(rq);
            rk = dpp_add<0x141>(rk); rq = dpp_add<0x141>(rq);
            rk = dpp_add<0x140>(rk); rq = dpp_add<0x140>(rq);

            float v = vva.x;
            f32x2 w01 = v * k0v, w23 = v * k1v;       // pre-alpha
            f32x2 d01 = s01 - w01, d23 = s23 - w23;   // pre-alpha

            // alpha = sigmoid(da*rk + a + ba); e = exp(-z) = exp2(dabar*rk + abar)
            float e = __builtin_amdgcn_exp2f(fmaf(dabar, rk, vva.y));
            float alpha = __builtin_amdgcn_rcpf(1.f + e);
            f32x2 a2 = {alpha, alpha};
            s01 = a2 * d01 + w01;   // s = w + alpha*(s-w)
            s23 = a2 * d23 + w23;

            float u1 = fmaf(-alpha, v, v);            // (1-alpha)*v
            float o = fmaf(alpha, rq, u1 * kq);       // S_new.q
            float so = __builtin_amdgcn_rcpf(1.f + __builtin_amdgcn_exp2f(o * NLOG2E));
            float ov = o * o * so;
            if (c == 0) Ol[tl][r] = ov;
        }
        WAIT_VM0;  // chunk j+1 staged a full chunk ago

        // dump chunk outputs: lane = local t, 4 rows as float4
        float4 t4 = *(const float4*)&Ol[lane][0];
        *(float4*)(out + ((size_t)(j * CH + lane) * BATCH + b) * NDIM + g * 4) = t4;

        if (j + 1 < T_STEPS / CH) {  // preload pipeline for next chunk
            int nb = cb ^ 1;
#pragma unroll
            for (int u = 0; u < 2; ++u) {
                f32x4 kk = *(const f32x4*)(&Kl[nb][u][c4]);
                f32x4 qq = *(const f32x4*)(&Ql[nb][u][c4]);
                k01[u] = kk.lo; k23[u] = kk.hi;
                q01[u] = qq.lo; q23[u] = qq.hi;
                va[u] = *(const f32x2*)&VAl[nb][u][r * 2];
                kqv[u] = KQl[nb][u];
            }
        }
    }

    float* so = Sout + ((size_t)b * NDIM + i) * NDIM + c4;
    *(float4*)so = float4{s01.x, s01.y, s23.x, s23.y};
}

extern "C" void kernel_launch(void* const* d_in, const int* in_sizes, int n_in,
                              void* d_out, int out_size, void* d_ws, size_t ws_size,
                              hipStream_t stream) {
    const float* x  = (const float*)d_in[0];
    const float* S0 = (const float*)d_in[1];
    const float* Wk = (const float*)d_in[2];
    const float* Wv = (const float*)d_in[3];
    const float* Wq = (const float*)d_in[4];
    const float* Wa = (const float*)d_in[5];
    const float* da = (const float*)d_in[6];
    const float* ba = (const float*)d_in[7];

    float* out = (float*)d_out;
    float* Sout = out + (size_t)T_STEPS * BATCH * NDIM;

    const size_t per = (size_t)M_TOTAL * NDIM;
    float* Kp  = (float*)d_ws;           // per floats
    float* Qp  = Kp + per;               // per
    float* VAi = Qp + per;               // 2*per (v, abar interleaved per row)
    float* kq  = VAi + 2 * per;          // M_TOTAL
    unsigned short* Wb = (unsigned short*)(kq + M_TOTAL);  // 512 KB bf16

    pack_w<<<dim3(256), dim3(256), 0, stream>>>(Wk, Wq, Wv, Wa, Wb);
    proj_kernel<<<dim3(M_TOTAL / 64), dim3(256), 0, stream>>>(x, Wb, ba, Kp, Qp, VAi);
    kq_kernel<<<dim3(M_TOTAL / 16), dim3(256), 0, stream>>>(Kp, Qp, kq);
    recur_kernel<<<dim3(16, BATCH), dim3(64), 0, stream>>>(Kp, Qp, VAi, kq, S0, da, out, Sout);
}